// Round 4
// baseline (2185.167 us; speedup 1.0000x reference)
//
#include <hip/hip_runtime.h>

#define NU 500000
#define NI 200000
#define NN (NU + NI)         // combined node count (users then items)
#define NE 2000000
#define HD 32
#define DF 256
#define OC 96                // output row stride = 3*H

typedef float        f4 __attribute__((ext_vector_type(4)));
typedef unsigned int u2 __attribute__((ext_vector_type(2)));
typedef unsigned int u4 __attribute__((ext_vector_type(4)));
typedef unsigned short ushort_t;

__device__ __forceinline__ float lrelu(float v){ return v >= 0.f ? v : 0.01f*v; }

// f32 -> bf16 round-to-nearest-even
__device__ __forceinline__ unsigned int f2bf(float f){
  unsigned int u = __float_as_uint(f);
  u += 0x7fffu + ((u >> 16) & 1u);
  return u >> 16;
}

__global__ void k_zero_i32(int* __restrict__ p, int n){
  int i = blockIdx.x*blockDim.x + threadIdx.x;
  if (i < n) p[i] = 0;
}

// final_user[:,0:32] = user_emb[user_ids]; also write bf16 compact table
__global__ void k_init_user(const int* __restrict__ ids, const float* __restrict__ emb,
                            float* __restrict__ outu, ushort_t* __restrict__ tbl){
  int i = blockIdx.x*blockDim.x + threadIdx.x;
  if (i >= NU) return;
  int uid = ids[i];
  const f4* s = (const f4*)(emb + (size_t)uid*HD);
  f4* d = (f4*)(outu + (size_t)i*OC);
  unsigned int pk[16];
  #pragma unroll
  for (int q = 0; q < 8; ++q) {
    f4 v = __builtin_nontemporal_load(s + q);
    __builtin_nontemporal_store(v, d + q);
    pk[2*q]   = f2bf(v.x) | (f2bf(v.y) << 16);
    pk[2*q+1] = f2bf(v.z) | (f2bf(v.w) << 16);
  }
  u4* t = (u4*)(tbl + (size_t)i*HD);
  #pragma unroll
  for (int q = 0; q < 4; ++q) {
    u4 v; v.x = pk[4*q]; v.y = pk[4*q+1]; v.z = pk[4*q+2]; v.w = pk[4*q+3];
    t[q] = v;
  }
}

// final_item[:,0:32] = item_emb[product_ids] + feat @ W^T + b ; + bf16 table
__global__ __launch_bounds__(512) void k_init_item(
    const int* __restrict__ ids, const float* __restrict__ emb,
    const float* __restrict__ feat, const float* __restrict__ W,
    const float* __restrict__ bias, float* __restrict__ outi,
    ushort_t* __restrict__ tbl){
  __shared__ float combo[256*34];
  int t = threadIdx.x;
  int r = t & 255;
  int seg = __builtin_amdgcn_readfirstlane(t >> 8);   // 0 or 1, wave-uniform
  int row = blockIdx.x*256 + r;
  bool valid = row < NI;
  float acc[HD];
  #pragma unroll
  for (int h = 0; h < HD; ++h) acc[h] = 0.f;

  if (valid) {
    const f4* f4p = (const f4*)(feat + (size_t)row*DF + seg*128);
    f4 a0 = __builtin_nontemporal_load(f4p);
    f4 a1 = __builtin_nontemporal_load(f4p + 1);
    for (int k0 = 0; k0 < 128; k0 += 8) {
      f4 n0 = {0,0,0,0}, n1 = {0,0,0,0};
      if (k0 + 8 < 128) {
        n0 = __builtin_nontemporal_load(f4p + (k0>>2) + 2);
        n1 = __builtin_nontemporal_load(f4p + (k0>>2) + 3);
      }
      float fv[8] = {a0.x,a0.y,a0.z,a0.w,a1.x,a1.y,a1.z,a1.w};
      #pragma unroll
      for (int kk = 0; kk < 8; ++kk) {
        #pragma unroll
        for (int h = 0; h < HD; ++h)
          acc[h] += fv[kk]*W[h*DF + seg*128 + k0 + kk];   // scalar (s_load) operand
      }
      a0 = n0; a1 = n1;
    }
  }
  if (seg == 1) {
    float2* c2 = (float2*)(combo + r*34);
    #pragma unroll
    for (int q = 0; q < 16; ++q) c2[q] = make_float2(acc[2*q], acc[2*q+1]);
  }
  __syncthreads();
  if (seg == 0 && valid) {
    const float2* c2 = (const float2*)(combo + r*34);
    #pragma unroll
    for (int q = 0; q < 16; ++q) { float2 v = c2[q]; acc[2*q] += v.x; acc[2*q+1] += v.y; }
    int pid = ids[row];
    const f4* ev = (const f4*)(emb + (size_t)pid*HD);
    const f4* bv = (const f4*)bias;
    f4* dst = (f4*)(outi + (size_t)row*OC);
    unsigned int pk[16];
    #pragma unroll
    for (int q = 0; q < 8; ++q) {
      f4 e = ev[q], b = bv[q];
      f4 o;
      o.x = acc[4*q+0]+e.x+b.x; o.y = acc[4*q+1]+e.y+b.y;
      o.z = acc[4*q+2]+e.z+b.z; o.w = acc[4*q+3]+e.w+b.w;
      __builtin_nontemporal_store(o, dst + q);
      pk[2*q]   = f2bf(o.x) | (f2bf(o.y) << 16);
      pk[2*q+1] = f2bf(o.z) | (f2bf(o.w) << 16);
    }
    u4* tb = (u4*)(tbl + (size_t)row*HD);
    #pragma unroll
    for (int q = 0; q < 4; ++q) {
      u4 v; v.x = pk[4*q]; v.y = pk[4*q+1]; v.z = pk[4*q+2]; v.w = pk[4*q+3];
      tb[q] = v;
    }
  }
}

// degree histogram over combined node ids (users 0..NU-1, items NU..NN-1)
__global__ void k_deg(const int* __restrict__ esrc, const int* __restrict__ edst,
                      int* __restrict__ cnt){
  int e = blockIdx.x*blockDim.x + threadIdx.x;
  if (e >= NE) return;
  int u = __builtin_nontemporal_load(esrc + e);
  int p = __builtin_nontemporal_load(edst + e);
  atomicAdd(cnt + u, 1);
  atomicAdd(cnt + NU + p, 1);
}

// ---- 3-kernel exclusive scan over cnt[NN] -> off[NN] ----
__global__ void k_scan1(const int* __restrict__ cnt, int* __restrict__ off,
                        int* __restrict__ part, int n){
  __shared__ int s[256];
  int t = threadIdx.x, i = blockIdx.x*256 + t;
  int v = (i < n) ? cnt[i] : 0;
  s[t] = v; __syncthreads();
  for (int o = 1; o < 256; o <<= 1) {
    int x = (t >= o) ? s[t-o] : 0;
    __syncthreads(); s[t] += x; __syncthreads();
  }
  if (i < n) off[i] = s[t] - v;
  if (t == 255) part[blockIdx.x] = s[255];
}

__global__ void k_scan2(int* __restrict__ part, int nb){
  __shared__ int s[256];
  __shared__ int carry;
  int t = threadIdx.x;
  if (t == 0) carry = 0;
  __syncthreads();
  for (int c0 = 0; c0 < nb; c0 += 256) {
    int i = c0 + t;
    int v = (i < nb) ? part[i] : 0;
    s[t] = v; __syncthreads();
    for (int o = 1; o < 256; o <<= 1) {
      int x = (t >= o) ? s[t-o] : 0;
      __syncthreads(); s[t] += x; __syncthreads();
    }
    int total = s[255];
    if (i < nb) part[i] = carry + s[t] - v;
    __syncthreads();
    if (t == 0) carry += total;
    __syncthreads();
  }
}

__global__ void k_scan3(int* __restrict__ off, const int* __restrict__ part, int n){
  int i = blockIdx.x*256 + threadIdx.x;
  if (i < n) off[i] += part[blockIdx.x];
}

// scatter edges into CSR neighbor lists
__global__ void k_scatter(const int* __restrict__ esrc, const int* __restrict__ edst,
                          const int* __restrict__ off, int* __restrict__ cur,
                          int* __restrict__ nbr){
  int e = blockIdx.x*blockDim.x + threadIdx.x;
  if (e >= NE) return;
  int u = __builtin_nontemporal_load(esrc + e);
  int p = __builtin_nontemporal_load(edst + e);
  int s1 = off[u]      + atomicAdd(cur + u,      1); nbr[s1] = p;
  int s2 = off[NU + p] + atomicAdd(cur + NU + p, 1); nbr[s2] = u;
}

// Fused pull-aggregate (bf16 table) + SAGE linear + leakyReLU.
// 8 threads/node, 4 cols each; gather unrolled x4; allgather 4->32 via shfl_xor.
__global__ void k_pull_fin(float* __restrict__ dstbase, int n, int nodebase,
                           const ushort_t* __restrict__ srctbl, int xoff, int outoff,
                           const int* __restrict__ off, const int* __restrict__ cnt,
                           const int* __restrict__ nbr,
                           const float* __restrict__ Wl, const float* __restrict__ bl,
                           const float* __restrict__ Wr, ushort_t* __restrict__ bftbl){
  int tid = blockIdx.x*256 + threadIdx.x;
  int node = tid >> 3;
  if (node >= n) return;
  int q = tid & 7;                 // cols q*4 .. q*4+3
  int gnode = nodebase + node;
  int deg = cnt[gnode];
  int start = off[gnode];

  // x (root) slice — NT, streaming
  f4 xv = __builtin_nontemporal_load((const f4*)(dstbase + (size_t)node*OC + xoff + q*4));

  const u2* sb = (const u2*)srctbl + q;   // row s -> sb[s*8]
  f4 a0 = {0,0,0,0}, a1 = a0, a2 = a0, a3 = a0;
  int j = 0;
  for (; j + 4 <= deg; j += 4) {
    int s0 = __builtin_nontemporal_load(nbr + start + j + 0);
    int s1 = __builtin_nontemporal_load(nbr + start + j + 1);
    int s2 = __builtin_nontemporal_load(nbr + start + j + 2);
    int s3 = __builtin_nontemporal_load(nbr + start + j + 3);
    u2 r0 = sb[(size_t)s0*8];
    u2 r1 = sb[(size_t)s1*8];
    u2 r2 = sb[(size_t)s2*8];
    u2 r3 = sb[(size_t)s3*8];
    a0.x += __uint_as_float(r0.x << 16); a0.y += __uint_as_float(r0.x & 0xffff0000u);
    a0.z += __uint_as_float(r0.y << 16); a0.w += __uint_as_float(r0.y & 0xffff0000u);
    a1.x += __uint_as_float(r1.x << 16); a1.y += __uint_as_float(r1.x & 0xffff0000u);
    a1.z += __uint_as_float(r1.y << 16); a1.w += __uint_as_float(r1.y & 0xffff0000u);
    a2.x += __uint_as_float(r2.x << 16); a2.y += __uint_as_float(r2.x & 0xffff0000u);
    a2.z += __uint_as_float(r2.y << 16); a2.w += __uint_as_float(r2.y & 0xffff0000u);
    a3.x += __uint_as_float(r3.x << 16); a3.y += __uint_as_float(r3.x & 0xffff0000u);
    a3.z += __uint_as_float(r3.y << 16); a3.w += __uint_as_float(r3.y & 0xffff0000u);
  }
  for (; j < deg; ++j) {
    int s = __builtin_nontemporal_load(nbr + start + j);
    u2 r = sb[(size_t)s*8];
    a0.x += __uint_as_float(r.x << 16); a0.y += __uint_as_float(r.x & 0xffff0000u);
    a0.z += __uint_as_float(r.y << 16); a0.w += __uint_as_float(r.y & 0xffff0000u);
  }
  a0 += a1 + a2 + a3;
  float inv = 1.f / (float)(deg < 1 ? 1 : deg);
  float m0[4] = {a0.x*inv, a0.y*inv, a0.z*inv, a0.w*inv};
  float x0[4] = {xv.x, xv.y, xv.z, xv.w};

  // allgather 4 -> 32 across the 8-thread group
  bool b1 = (q & 1), b2 = (q & 2), b4 = (q & 4);
  float tm1[8], tx1[8];
  #pragma unroll
  for (int k = 0; k < 4; ++k) {
    float om = __shfl_xor(m0[k], 1), ox = __shfl_xor(x0[k], 1);
    tm1[k]   = b1 ? om    : m0[k];  tx1[k]   = b1 ? ox    : x0[k];
    tm1[k+4] = b1 ? m0[k] : om;     tx1[k+4] = b1 ? x0[k] : ox;
  }
  float tm2[16], tx2[16];
  #pragma unroll
  for (int k = 0; k < 8; ++k) {
    float om = __shfl_xor(tm1[k], 2), ox = __shfl_xor(tx1[k], 2);
    tm2[k]   = b2 ? om     : tm1[k];  tx2[k]   = b2 ? ox     : tx1[k];
    tm2[k+8] = b2 ? tm1[k] : om;      tx2[k+8] = b2 ? tx1[k] : ox;
  }
  float m[32], x[32];
  #pragma unroll
  for (int k = 0; k < 16; ++k) {
    float om = __shfl_xor(tm2[k], 4), ox = __shfl_xor(tx2[k], 4);
    m[k]    = b4 ? om     : tm2[k];  x[k]    = b4 ? ox     : tx2[k];
    m[k+16] = b4 ? tm2[k] : om;      x[k+16] = b4 ? tx2[k] : ox;
  }

  // y[h] for h = q*4 .. q*4+3
  float y[4];
  #pragma unroll
  for (int k = 0; k < 4; ++k) {
    int h = q*4 + k;
    float s = bl[h];
    const f4* wl = (const f4*)(Wl + h*HD);
    const f4* wr = (const f4*)(Wr + h*HD);
    #pragma unroll
    for (int j4 = 0; j4 < 8; ++j4) {
      f4 wv = wl[j4];
      s += m[4*j4+0]*wv.x + m[4*j4+1]*wv.y + m[4*j4+2]*wv.z + m[4*j4+3]*wv.w;
    }
    #pragma unroll
    for (int j4 = 0; j4 < 8; ++j4) {
      f4 wv = wr[j4];
      s += x[4*j4+0]*wv.x + x[4*j4+1]*wv.y + x[4*j4+2]*wv.z + x[4*j4+3]*wv.w;
    }
    y[k] = lrelu(s);
  }
  f4 yo; yo.x = y[0]; yo.y = y[1]; yo.z = y[2]; yo.w = y[3];
  __builtin_nontemporal_store(yo, (f4*)(dstbase + (size_t)node*OC + outoff + q*4));
  if (bftbl) {
    u2 pv;
    pv.x = f2bf(y[0]) | (f2bf(y[1]) << 16);
    pv.y = f2bf(y[2]) | (f2bf(y[3]) << 16);
    *((u2*)bftbl + (size_t)node*8 + q) = pv;   // normal store: keep in cache for next pull
  }
}

extern "C" void kernel_launch(void* const* d_in, const int* in_sizes, int n_in,
                              void* d_out, int out_size, void* d_ws, size_t ws_size,
                              hipStream_t stream) {
  const int*   user_ids = (const int*)d_in[0];
  const int*   prod_ids = (const int*)d_in[1];
  const float* feat     = (const float*)d_in[2];
  const int*   er       = (const int*)d_in[3];   // [2, NE]: row0 = user, row1 = item
  const float* uemb     = (const float*)d_in[5];
  const float* iemb     = (const float*)d_in[6];
  const float* fW       = (const float*)d_in[7];
  const float* fb       = (const float*)d_in[8];
  const float* Wl_up1 = (const float*)d_in[9];
  const float* bl_up1 = (const float*)d_in[10];
  const float* Wr_up1 = (const float*)d_in[11];
  const float* Wl_pu1 = (const float*)d_in[12];
  const float* bl_pu1 = (const float*)d_in[13];
  const float* Wr_pu1 = (const float*)d_in[14];
  const float* Wl_up2 = (const float*)d_in[15];
  const float* bl_up2 = (const float*)d_in[16];
  const float* Wr_up2 = (const float*)d_in[17];
  const float* Wl_pu2 = (const float*)d_in[18];
  const float* bl_pu2 = (const float*)d_in[19];
  const float* Wr_pu2 = (const float*)d_in[20];

  float* outu = (float*)d_out;
  float* outi = outu + (size_t)NU*OC;

  // workspace: ints cnt[NN] | cur[NN] | off[NN] | part[2736] | nbr[2*NE],
  // then bf16 tables A (NU*32: xu then u1) | B (NI*32: xp) | C (NI*32: p1)
  int* cnt  = (int*)d_ws;
  int* cur  = cnt + NN;
  int* off  = cur + NN;
  int* part = off + NN;
  int* nbr  = part + 2736;
  ushort_t* tblA = (ushort_t*)(nbr + 2*NE);
  ushort_t* tblB = tblA + (size_t)NU*HD;
  ushort_t* tblC = tblB + (size_t)NI*HD;

  const int* er_src = er;        // users
  const int* er_dst = er + NE;   // items

  const int B = 256;
  const int NB1 = (NN + 255)/256;

  k_zero_i32<<<(2*NN + B - 1)/B, B, 0, stream>>>(cnt, 2*NN);
  k_deg<<<(NE + B - 1)/B, B, 0, stream>>>(er_src, er_dst, cnt);
  k_scan1<<<NB1, B, 0, stream>>>(cnt, off, part, NN);
  k_scan2<<<1, B, 0, stream>>>(part, NB1);
  k_scan3<<<NB1, B, 0, stream>>>(off, part, NN);
  k_scatter<<<(NE + B - 1)/B, B, 0, stream>>>(er_src, er_dst, off, cur, nbr);

  k_init_user<<<(NU + B - 1)/B, B, 0, stream>>>(user_ids, uemb, outu, tblA);
  k_init_item<<<(NI + 255)/256, 512, 0, stream>>>(prod_ids, iemb, feat, fW, fb, outi, tblB);

  // layer 1: items pull xu (tblA) -> writes p1 + tblC; users pull xp (tblB) -> u1 + tblA
  k_pull_fin<<<((size_t)NI*8 + B - 1)/B, B, 0, stream>>>(outi, NI, NU, tblA, 0, 32,
                                     off, cnt, nbr, Wl_up1, bl_up1, Wr_up1, tblC);
  k_pull_fin<<<((size_t)NU*8 + B - 1)/B, B, 0, stream>>>(outu, NU, 0, tblB, 0, 32,
                                     off, cnt, nbr, Wl_pu1, bl_pu1, Wr_pu1, tblA);
  // layer 2: items pull u1 (tblA); users pull p1 (tblC)
  k_pull_fin<<<((size_t)NI*8 + B - 1)/B, B, 0, stream>>>(outi, NI, NU, tblA, 32, 64,
                                     off, cnt, nbr, Wl_up2, bl_up2, Wr_up2, (ushort_t*)nullptr);
  k_pull_fin<<<((size_t)NU*8 + B - 1)/B, B, 0, stream>>>(outu, NU, 0, tblC, 32, 64,
                                     off, cnt, nbr, Wl_pu2, bl_pu2, Wr_pu2, (ushort_t*)nullptr);
}